// Round 10
// baseline (523.931 us; speedup 1.0000x reference)
//
#include <hip/hip_runtime.h>
#include <math.h>

#define GAMMA_   0.97f
#define LAM_     0.95f
#define EPSILON_ 0.3f
#define HLOG2PI_ 0.91893853320467274f
#define LOG2C_   0.69314718055994531f
#define LOG1P2_  0.18232155679395463f
#define LOG0P8_  (-0.22314355131420976f)

typedef unsigned short u16;
typedef unsigned int   u32;
typedef _Float16 half8 __attribute__((ext_vector_type(8)));
typedef _Float16 half4 __attribute__((ext_vector_type(4)));
typedef __attribute__((ext_vector_type(4))) float floatx4;
typedef __attribute__((ext_vector_type(8))) float floatx8;

constexpr int  TT     = 1024;
constexpr long ROWS_P = (long)TT * 256;          // 262144
constexpr long ROWS_V = (long)(TT + 1) * 256;    // 262400

// ---- fragment workspace layout (u16 offsets from ws base) ----
constexpr long FR_W0P_HI = 0;        // NT16 KS2  -> 16384
constexpr long FR_W0P_LO = 16384;
constexpr long FR_W1P_HI = 32768;    // NT16 KS8  -> 65536
constexpr long FR_W1P_LO = 98304;
constexpr long FR_W2P_HI = 163840;   // NT1  KS8  -> 4096
constexpr long FR_W2P_LO = 167936;
constexpr long FR_W0V_HI = 172032;
constexpr long FR_W0V_LO = 188416;
constexpr long FR_W1V_HI = 204800;
constexpr long FR_W1V_LO = 270336;
constexpr long FR_W2V_HI = 335872;
constexpr long FR_W2V_LO = 339968;
constexpr long FR_TOTAL  = 344064;   // u16 elems

// ---- float workspace (offsets from (float*)ws + FR_TOTAL/2) ----
constexpr long WS_ACC  = 0;                 // 32 (accum[24] doubles as ctr)
constexpr long WS_INV  = 32;                // 64
constexpr long WS_ADV  = 96;                // 262144
constexpr long WS_BASE = WS_ADV + ROWS_P;   // 262400
constexpr long WS_GA   = WS_BASE + ROWS_V;  // 8192
constexpr long WS_GP   = WS_GA + 8192;
constexpr long WS_BANK = WS_GP + 8192;      // 32 banks x 32 floats = 1024
constexpr long WS_GLP  = WS_BANK + 1024;    // 262144
constexpr long WS_LLP  = WS_GLP + ROWS_P;   // 262144
constexpr long WS_BLP  = WS_LLP + ROWS_P;   // 262144

// accum slots: 3 adv_sum, 4 adv2_sum, 5 vmx2_sum; [24] = epi2 block ctr.
// banked accumB slots: 0 kl, 1 kl_m, 2 ent (fused); 6 gp, 7 lp (epi2).

__device__ __forceinline__ float softplus_f(float x) {
  return (x > 20.f) ? x : log1pf(expf(x));
}
__device__ __forceinline__ float silu_f(float x) {
  return x * __builtin_amdgcn_rcpf(1.f + __expf(-x));
}
__device__ __forceinline__ float clamp30(float x) {
  return fminf(1e30f, fmaxf(-1e30f, x));
}

// ---------------- weight -> split-fp16 MFMA fragments (+ prep fold) ----
__global__ void convert_kernel(const float* __restrict__ pw0,
                               const float* __restrict__ pw1,
                               const float* __restrict__ pw2,
                               const float* __restrict__ vw0,
                               const float* __restrict__ vw1,
                               const float* __restrict__ vw2,
                               const float* __restrict__ rv,
                               float* __restrict__ inv_std,
                               float* __restrict__ accum,
                               float* __restrict__ accumB,
                               u16* __restrict__ frag) {
  if (blockIdx.x == 0) {               // prep fold: saves one launch
    int t = threadIdx.x;
    if (t < 32) accum[t] = 0.f;        // zeroes ctr at [24] too
    for (int i = t; i < 1024; i += 256) accumB[i] = 0.f;
    if (t < 64) {
      float var = rv[t] / 1000001.0f;
      var = fminf(1e6f, fmaxf(1e-6f, var));
      inv_std[t] = 1.f / sqrtf(var);
    }
  }
  int idx = blockIdx.x * 256 + threadIdx.x;   // 0..172031
  const float* W; int kslog, K, nvalid; long hioff, looff; int e;
  if (idx < 16384)       { W = pw0; e = idx;          kslog = 1; K = 64;  nvalid = 256; hioff = FR_W0P_HI; looff = FR_W0P_LO; }
  else if (idx < 81920)  { W = pw1; e = idx - 16384;  kslog = 3; K = 256; nvalid = 256; hioff = FR_W1P_HI; looff = FR_W1P_LO; }
  else if (idx < 86016)  { W = pw2; e = idx - 81920;  kslog = 3; K = 256; nvalid = 16;  hioff = FR_W2P_HI; looff = FR_W2P_LO; }
  else if (idx < 102400) { W = vw0; e = idx - 86016;  kslog = 1; K = 64;  nvalid = 256; hioff = FR_W0V_HI; looff = FR_W0V_LO; }
  else if (idx < 167936) { W = vw1; e = idx - 102400; kslog = 3; K = 256; nvalid = 256; hioff = FR_W1V_HI; looff = FR_W1V_LO; }
  else                   { W = vw2; e = idx - 167936; kslog = 3; K = 256; nvalid = 1;   hioff = FR_W2V_HI; looff = FR_W2V_LO; }
  int j    = e & 7;
  int lane = (e >> 3) & 63;
  int ks   = (e >> 9) & ((1 << kslog) - 1);
  int nt   = e >> (9 + kslog);
  int n = nt * 16 + (lane & 15);
  int k = ks * 32 + ((lane >> 4) << 3) + j;
  float w = (n < nvalid) ? W[n * K + k] : 0.f;
  _Float16 hi = (_Float16)w;
  _Float16 lo = (_Float16)(w - (float)hi);
  frag[hioff + e] = *(u16*)&hi;
  frag[looff + e] = *(u16*)&lo;
}

// LDS strides (fp16 units); multiples of 8 (16B-aligned rows)
constexpr int SX = 72;    // X row stride
constexpr int SH = 264;   // H row stride
constexpr int SO = 20;    // OUTT row stride (floats)

// =====================================================================
// Fused forward R10: ONE dispatch runs policy-forward blocks (8192) and
// value blocks (4100), interleaved 2:1 for per-CU phase diversity.
// Policy blocks: forward + glp/llp/blp store + kl/kl_m/ent banked sums
// (adv-INdependent part only -> runs before GAE). gp/lp deferred to epi2.
// Tile economy = R4/R9 champion (4 waves, acc[4][4], launch_bounds(256,3)).
// =====================================================================
__global__ __launch_bounds__(256, 3)
void fused_fwd_kernel(const float* __restrict__ obs,
                      const float* __restrict__ pobs,
                      const float* __restrict__ rm,
                      const float* __restrict__ inv_std,
                      const u16* __restrict__ frag,
                      const float* __restrict__ pb0,
                      const float* __restrict__ pb1,
                      const float* __restrict__ pb2,
                      const float* __restrict__ vb0,
                      const float* __restrict__ vb1,
                      const float* __restrict__ vb2,
                      const float* __restrict__ logits,
                      const float* __restrict__ action,
                      const float* __restrict__ noise,
                      float* __restrict__ baseline,
                      float* __restrict__ glpA,
                      float* __restrict__ llpA,
                      float* __restrict__ blpA,
                      float* __restrict__ accumB) {
  __shared__ __align__(16) _Float16 H[64 * SH];   // 33792 B
  __shared__ __align__(16) float OUTT[64 * SO];   // 5120 B
  __shared__ float red[192];                      // 768 B

  const int tid  = threadIdx.x;
  const int lane = tid & 63;
  const int wv   = tid >> 6;
  const int lm   = lane & 15;
  const int lq   = lane >> 4;

  // ---- block role mapping: groups of 3 = [P,P,V] ----
  int bid = blockIdx.x;
  bool isP; long sub;
  if (bid < 12288) {
    int g = bid / 3, r = bid - g * 3;
    if (r < 2) { isP = true;  sub = (long)g * 2 + r; }
    else       { isP = false; sub = g; }
  } else { isP = false; sub = 4096 + (bid - 12288); }

  _Float16* X = H;

  if (isP) {
    // ================= POLICY-FORWARD BLOCK =================
    const long row0 = sub * 32;
    #pragma unroll
    for (int it = 0; it < 2; ++it) {
      int flat = it * 256 + tid;
      int vr = flat >> 3;
      int f0 = (flat & 7) * 8;
      const float* src = (vr < 32) ? obs : pobs;
      floatx8 v  = *(const floatx8*)&src[(row0 + (vr & 31)) * 64 + f0];
      floatx8 m  = *(const floatx8*)&rm[f0];
      floatx8 is = *(const floatx8*)&inv_std[f0];
      half8 h;
      #pragma unroll
      for (int j = 0; j < 8; ++j)
        h[j] = (_Float16)fminf(5.f, fmaxf(-5.f, (v[j] - m[j]) * is[j]));
      *(half8*)&X[vr * SX + f0] = h;
    }

    // early prefetch of epilogue inputs (no adv/accum — not ready yet)
    const int  er   = tid >> 3;
    const int  ed   = tid & 7;
    const long erow = row0 + er;
    float pf_a   = action[erow * 8 + ed];
    float pf_loc = logits[erow * 16 + ed];
    float pf_sr  = logits[erow * 16 + 8 + ed];
    float pf_nd  = noise[erow * 8 + ed];

    const half8* B0h = (const half8*)(frag + FR_W0P_HI);
    const half8* B0l = (const half8*)(frag + FR_W0P_LO);
    half8 B0hr[2][4], B0lr[2][4];
    #pragma unroll
    for (int ks = 0; ks < 2; ++ks)
      #pragma unroll
      for (int nt = 0; nt < 4; ++nt) {
        int ntg = wv * 4 + nt;
        B0hr[ks][nt] = B0h[(ntg * 2 + ks) * 64 + lane];
        B0lr[ks][nt] = B0l[(ntg * 2 + ks) * 64 + lane];
      }

    floatx4 acc[4][4];
    #pragma unroll
    for (int nt = 0; nt < 4; ++nt) {
      floatx4 bz = *(const floatx4*)&pb0[(wv * 4 + nt) * 16 + lq * 4];
      #pragma unroll
      for (int mt = 0; mt < 4; ++mt) acc[mt][nt] = bz;
    }
    __syncthreads();

    #pragma unroll
    for (int ks = 0; ks < 2; ++ks) {
      half8 A[4];
      #pragma unroll
      for (int mt = 0; mt < 4; ++mt)
        A[mt] = *(const half8*)&X[(mt * 16 + lm) * SX + ks * 32 + lq * 8];
      __builtin_amdgcn_s_setprio(1);
      #pragma unroll
      for (int mt = 0; mt < 4; ++mt)
        #pragma unroll
        for (int nt = 0; nt < 4; ++nt)
          acc[mt][nt] = __builtin_amdgcn_mfma_f32_16x16x32_f16(B0hr[ks][nt], A[mt], acc[mt][nt], 0, 0, 0);
      #pragma unroll
      for (int mt = 0; mt < 4; ++mt)
        #pragma unroll
        for (int nt = 0; nt < 4; ++nt)
          acc[mt][nt] = __builtin_amdgcn_mfma_f32_16x16x32_f16(B0lr[ks][nt], A[mt], acc[mt][nt], 0, 0, 0);
      __builtin_amdgcn_s_setprio(0);
    }

    const half8* B1h = (const half8*)(frag + FR_W1P_HI);
    const half8* B1l = (const half8*)(frag + FR_W1P_LO);
    half8 Bh[4], Bl[4], Bhn[4], Bln[4];
    #pragma unroll
    for (int nt = 0; nt < 4; ++nt) {
      int ntg = wv * 4 + nt;
      Bh[nt] = B1h[(ntg * 8) * 64 + lane];
      Bl[nt] = B1l[(ntg * 8) * 64 + lane];
    }

    __syncthreads();
    #pragma unroll
    for (int nt = 0; nt < 4; ++nt) {
      int colbase = (wv * 4 + nt) * 16 + lq * 4;
      #pragma unroll
      for (int mt = 0; mt < 4; ++mt) {
        int row = mt * 16 + lm;
        half4 h;
        #pragma unroll
        for (int reg = 0; reg < 4; ++reg)
          h[reg] = (_Float16)silu_f(acc[mt][nt][reg]);
        *(half4*)&H[row * SH + colbase] = h;
      }
    }
    #pragma unroll
    for (int nt = 0; nt < 4; ++nt) {
      floatx4 bz = *(const floatx4*)&pb1[(wv * 4 + nt) * 16 + lq * 4];
      #pragma unroll
      for (int mt = 0; mt < 4; ++mt) acc[mt][nt] = bz;
    }
    __syncthreads();

    #pragma unroll 1
    for (int ks = 0; ks < 8; ++ks) {
      if (ks < 7) {
        #pragma unroll
        for (int nt = 0; nt < 4; ++nt) {
          int ntg = wv * 4 + nt;
          Bhn[nt] = B1h[(ntg * 8 + ks + 1) * 64 + lane];
          Bln[nt] = B1l[(ntg * 8 + ks + 1) * 64 + lane];
        }
      }
      half8 A[4];
      #pragma unroll
      for (int mt = 0; mt < 4; ++mt)
        A[mt] = *(const half8*)&H[(mt * 16 + lm) * SH + ks * 32 + lq * 8];
      __builtin_amdgcn_s_setprio(1);
      #pragma unroll
      for (int mt = 0; mt < 4; ++mt)
        #pragma unroll
        for (int nt = 0; nt < 4; ++nt)
          acc[mt][nt] = __builtin_amdgcn_mfma_f32_16x16x32_f16(Bh[nt], A[mt], acc[mt][nt], 0, 0, 0);
      #pragma unroll
      for (int mt = 0; mt < 4; ++mt)
        #pragma unroll
        for (int nt = 0; nt < 4; ++nt)
          acc[mt][nt] = __builtin_amdgcn_mfma_f32_16x16x32_f16(Bl[nt], A[mt], acc[mt][nt], 0, 0, 0);
      __builtin_amdgcn_s_setprio(0);
      if (ks < 7) {
        #pragma unroll
        for (int nt = 0; nt < 4; ++nt) { Bh[nt] = Bhn[nt]; Bl[nt] = Bln[nt]; }
      }
    }

    const half8* B2h = (const half8*)(frag + FR_W2P_HI);
    const half8* B2l = (const half8*)(frag + FR_W2P_LO);
    half8 B2hr[8], B2lr[8];
    #pragma unroll
    for (int ks = 0; ks < 8; ++ks) {
      B2hr[ks] = B2h[ks * 64 + lane];
      B2lr[ks] = B2l[ks * 64 + lane];
    }

    __syncthreads();
    #pragma unroll
    for (int nt = 0; nt < 4; ++nt) {
      int colbase = (wv * 4 + nt) * 16 + lq * 4;
      #pragma unroll
      for (int mt = 0; mt < 4; ++mt) {
        int row = mt * 16 + lm;
        half4 h;
        #pragma unroll
        for (int reg = 0; reg < 4; ++reg)
          h[reg] = (_Float16)silu_f(acc[mt][nt][reg]);
        *(half4*)&H[row * SH + colbase] = h;
      }
    }
    __syncthreads();

    {
      floatx4 c3a = (floatx4){0.f,0.f,0.f,0.f};
      floatx4 c3b = (floatx4){0.f,0.f,0.f,0.f};
      __builtin_amdgcn_s_setprio(1);
      #pragma unroll
      for (int ks = 0; ks < 8; ks += 2) {
        half8 A0 = *(const half8*)&H[(wv * 16 + lm) * SH + ks * 32 + lq * 8];
        half8 A1 = *(const half8*)&H[(wv * 16 + lm) * SH + (ks + 1) * 32 + lq * 8];
        c3a = __builtin_amdgcn_mfma_f32_16x16x32_f16(B2hr[ks],     A0, c3a, 0, 0, 0);
        c3b = __builtin_amdgcn_mfma_f32_16x16x32_f16(B2hr[ks + 1], A1, c3b, 0, 0, 0);
        c3a = __builtin_amdgcn_mfma_f32_16x16x32_f16(B2lr[ks],     A0, c3a, 0, 0, 0);
        c3b = __builtin_amdgcn_mfma_f32_16x16x32_f16(B2lr[ks + 1], A1, c3b, 0, 0, 0);
      }
      __builtin_amdgcn_s_setprio(0);
      floatx4 bias = *(const floatx4*)&pb2[lq * 4];
      floatx4 o = c3a + c3b + bias;
      #pragma unroll
      for (int reg = 0; reg < 4; ++reg)
        OUTT[(wv * 16 + lm) * SO + lq * 4 + reg] = o[reg];
    }
    __syncthreads();

    // ---- epilogue (adv-independent): glp/llp/blp + kl/kl_m/ent ----
    {
      int r = er, d = ed;
      float gl  = OUTT[r * SO + d];
      float gsr = OUTT[r * SO + 8 + d];
      float ll  = OUTT[(32 + r) * SO + d];
      float lsr = OUTT[(32 + r) * SO + 8 + d];
      float a   = pf_a;
      float loc = pf_loc;
      float sr  = pf_sr;
      float nd  = pf_nd;

      float gs = softplus_f(gsr) + 1e-3f;
      float ls = softplus_f(lsr) + 1e-3f;
      float sc = softplus_f(sr) + 1e-3f;
      float ldj = 2.f * (LOG2C_ - a - softplus_f(-2.f * a));
      float lgs = logf(gs), lls = logf(ls), lsc = logf(sc);
      float zg = (a - gl) / gs;
      float zl = (a - ll) / ls;
      float z  = (a - loc) / sc;
      float glp = -0.5f * zg * zg - lgs - HLOG2PI_ - ldj;
      float llp = -0.5f * zl * zl - lls - HLOG2PI_ - ldj;
      float blp = -0.5f * z * z - lsc - HLOG2PI_ - ldj;
      float ratio = gs / ls;
      float vr = ratio * ratio;
      float t1 = (gl - ll) / ls; t1 *= t1;
      float kl = 0.5f * (vr + t1 - 1.f) - (lgs - lls);
      float dist = loc + sc * nd;
      float ent = 0.5f + HLOG2PI_ + lsc
                + 2.f * (LOG2C_ - dist - softplus_f(-2.f * dist));

      #pragma unroll
      for (int o = 4; o > 0; o >>= 1) {
        glp += __shfl_down(glp, o, 8);
        llp += __shfl_down(llp, o, 8);
        blp += __shfl_down(blp, o, 8);
        kl  += __shfl_down(kl, o, 8);
        ent += __shfl_down(ent, o, 8);
      }

      if (d == 0) {
        kl *= 0.125f;
        kl  = clamp30(kl);
        ent = clamp30(ent);
        float diff = glp - llp;
        float m = (diff > LOG1P2_ || diff < LOG0P8_) ? 1.f : 0.f;
        red[r]        = kl;
        red[32 + r]   = kl * m;
        red[64 + r]   = ent;
        red[96 + r]   = glp;
        red[128 + r]  = llp;
        red[160 + r]  = blp;
      }
    }
    __syncthreads();
    // coalesced row-result stores
    if (tid < 96) {
      int a = tid >> 5, i = tid & 31;
      float v = red[96 + tid];
      float* dst = (a == 0) ? glpA : (a == 1) ? llpA : blpA;
      dst[row0 + i] = v;
    }
    if (tid < 32) {
      float s0 = red[tid], s1 = red[32 + tid], s2 = red[64 + tid];
      #pragma unroll
      for (int o = 16; o > 0; o >>= 1) {
        s0 += __shfl_down(s0, o, 32);
        s1 += __shfl_down(s1, o, 32);
        s2 += __shfl_down(s2, o, 32);
      }
      if (tid == 0) {
        float* bank = accumB + (bid & 31) * 32;
        atomicAdd(&bank[0], s0);
        atomicAdd(&bank[1], s1);
        atomicAdd(&bank[2], s2);
      }
    }
  } else {
    // ================= VALUE BLOCK =================
    const long row0 = sub * 64;
    #pragma unroll
    for (int it = 0; it < 2; ++it) {
      int flat = it * 256 + tid;
      int vr = flat >> 3;
      int f0 = (flat & 7) * 8;
      floatx8 v  = *(const floatx8*)&obs[(row0 + vr) * 64 + f0];
      floatx8 m  = *(const floatx8*)&rm[f0];
      floatx8 is = *(const floatx8*)&inv_std[f0];
      half8 h;
      #pragma unroll
      for (int j = 0; j < 8; ++j)
        h[j] = (_Float16)fminf(5.f, fmaxf(-5.f, (v[j] - m[j]) * is[j]));
      *(half8*)&X[vr * SX + f0] = h;
    }

    const half8* B0h = (const half8*)(frag + FR_W0V_HI);
    const half8* B0l = (const half8*)(frag + FR_W0V_LO);
    half8 B0hr[2][4], B0lr[2][4];
    #pragma unroll
    for (int ks = 0; ks < 2; ++ks)
      #pragma unroll
      for (int nt = 0; nt < 4; ++nt) {
        int ntg = wv * 4 + nt;
        B0hr[ks][nt] = B0h[(ntg * 2 + ks) * 64 + lane];
        B0lr[ks][nt] = B0l[(ntg * 2 + ks) * 64 + lane];
      }

    floatx4 acc[4][4];
    #pragma unroll
    for (int nt = 0; nt < 4; ++nt) {
      floatx4 bz = *(const floatx4*)&vb0[(wv * 4 + nt) * 16 + lq * 4];
      #pragma unroll
      for (int mt = 0; mt < 4; ++mt) acc[mt][nt] = bz;
    }
    __syncthreads();

    #pragma unroll
    for (int ks = 0; ks < 2; ++ks) {
      half8 A[4];
      #pragma unroll
      for (int mt = 0; mt < 4; ++mt)
        A[mt] = *(const half8*)&X[(mt * 16 + lm) * SX + ks * 32 + lq * 8];
      __builtin_amdgcn_s_setprio(1);
      #pragma unroll
      for (int mt = 0; mt < 4; ++mt)
        #pragma unroll
        for (int nt = 0; nt < 4; ++nt)
          acc[mt][nt] = __builtin_amdgcn_mfma_f32_16x16x32_f16(B0hr[ks][nt], A[mt], acc[mt][nt], 0, 0, 0);
      #pragma unroll
      for (int mt = 0; mt < 4; ++mt)
        #pragma unroll
        for (int nt = 0; nt < 4; ++nt)
          acc[mt][nt] = __builtin_amdgcn_mfma_f32_16x16x32_f16(B0lr[ks][nt], A[mt], acc[mt][nt], 0, 0, 0);
      __builtin_amdgcn_s_setprio(0);
    }

    const half8* B1h = (const half8*)(frag + FR_W1V_HI);
    const half8* B1l = (const half8*)(frag + FR_W1V_LO);
    half8 Bh[4], Bl[4], Bhn[4], Bln[4];
    #pragma unroll
    for (int nt = 0; nt < 4; ++nt) {
      int ntg = wv * 4 + nt;
      Bh[nt] = B1h[(ntg * 8) * 64 + lane];
      Bl[nt] = B1l[(ntg * 8) * 64 + lane];
    }

    __syncthreads();
    #pragma unroll
    for (int nt = 0; nt < 4; ++nt) {
      int colbase = (wv * 4 + nt) * 16 + lq * 4;
      #pragma unroll
      for (int mt = 0; mt < 4; ++mt) {
        int row = mt * 16 + lm;
        half4 h;
        #pragma unroll
        for (int reg = 0; reg < 4; ++reg)
          h[reg] = (_Float16)silu_f(acc[mt][nt][reg]);
        *(half4*)&H[row * SH + colbase] = h;
      }
    }
    #pragma unroll
    for (int nt = 0; nt < 4; ++nt) {
      floatx4 bz = *(const floatx4*)&vb1[(wv * 4 + nt) * 16 + lq * 4];
      #pragma unroll
      for (int mt = 0; mt < 4; ++mt) acc[mt][nt] = bz;
    }
    __syncthreads();

    #pragma unroll 1
    for (int ks = 0; ks < 8; ++ks) {
      if (ks < 7) {
        #pragma unroll
        for (int nt = 0; nt < 4; ++nt) {
          int ntg = wv * 4 + nt;
          Bhn[nt] = B1h[(ntg * 8 + ks + 1) * 64 + lane];
          Bln[nt] = B1l[(ntg * 8 + ks + 1) * 64 + lane];
        }
      }
      half8 A[4];
      #pragma unroll
      for (int mt = 0; mt < 4; ++mt)
        A[mt] = *(const half8*)&H[(mt * 16 + lm) * SH + ks * 32 + lq * 8];
      __builtin_amdgcn_s_setprio(1);
      #pragma unroll
      for (int mt = 0; mt < 4; ++mt)
        #pragma unroll
        for (int nt = 0; nt < 4; ++nt)
          acc[mt][nt] = __builtin_amdgcn_mfma_f32_16x16x32_f16(Bh[nt], A[mt], acc[mt][nt], 0, 0, 0);
      #pragma unroll
      for (int mt = 0; mt < 4; ++mt)
        #pragma unroll
        for (int nt = 0; nt < 4; ++nt)
          acc[mt][nt] = __builtin_amdgcn_mfma_f32_16x16x32_f16(Bl[nt], A[mt], acc[mt][nt], 0, 0, 0);
      __builtin_amdgcn_s_setprio(0);
      if (ks < 7) {
        #pragma unroll
        for (int nt = 0; nt < 4; ++nt) { Bh[nt] = Bhn[nt]; Bl[nt] = Bln[nt]; }
      }
    }

    const half8* B2h = (const half8*)(frag + FR_W2V_HI);
    const half8* B2l = (const half8*)(frag + FR_W2V_LO);
    half8 B2hr[8], B2lr[8];
    #pragma unroll
    for (int ks = 0; ks < 8; ++ks) {
      B2hr[ks] = B2h[ks * 64 + lane];
      B2lr[ks] = B2l[ks * 64 + lane];
    }

    __syncthreads();
    #pragma unroll
    for (int nt = 0; nt < 4; ++nt) {
      int colbase = (wv * 4 + nt) * 16 + lq * 4;
      #pragma unroll
      for (int mt = 0; mt < 4; ++mt) {
        int row = mt * 16 + lm;
        half4 h;
        #pragma unroll
        for (int reg = 0; reg < 4; ++reg)
          h[reg] = (_Float16)silu_f(acc[mt][nt][reg]);
        *(half4*)&H[row * SH + colbase] = h;
      }
    }
    __syncthreads();

    {
      floatx4 c3a = (floatx4){0.f,0.f,0.f,0.f};
      floatx4 c3b = (floatx4){0.f,0.f,0.f,0.f};
      __builtin_amdgcn_s_setprio(1);
      #pragma unroll
      for (int ks = 0; ks < 8; ks += 2) {
        half8 A0 = *(const half8*)&H[(wv * 16 + lm) * SH + ks * 32 + lq * 8];
        half8 A1 = *(const half8*)&H[(wv * 16 + lm) * SH + (ks + 1) * 32 + lq * 8];
        c3a = __builtin_amdgcn_mfma_f32_16x16x32_f16(B2hr[ks],     A0, c3a, 0, 0, 0);
        c3b = __builtin_amdgcn_mfma_f32_16x16x32_f16(B2hr[ks + 1], A1, c3b, 0, 0, 0);
        c3a = __builtin_amdgcn_mfma_f32_16x16x32_f16(B2lr[ks],     A0, c3a, 0, 0, 0);
        c3b = __builtin_amdgcn_mfma_f32_16x16x32_f16(B2lr[ks + 1], A1, c3b, 0, 0, 0);
      }
      __builtin_amdgcn_s_setprio(0);
      if (lq == 0) baseline[row0 + wv * 16 + lm] = c3a[0] + c3b[0] + vb2[0];
    }
  }
}

// ---------------- GAE segmented scan ----------------
__global__ void gae_phase1(const float* __restrict__ reward,
                           const float* __restrict__ done,
                           const float* __restrict__ trunc,
                           const float* __restrict__ baseline,
                           float* __restrict__ A, float* __restrict__ P) {
  int s = blockIdx.x, b = threadIdx.x;
  float Aa = 0.f, Pp = 1.f;
  for (int t = (s + 1) * 32 - 1; t >= s * 32; --t) {
    int idx = t * 256 + b;
    float r = reward[idx], d = done[idx], tr = trunc[idx];
    float tm = 1.f - tr;
    float te = d * tm;
    float bl = baseline[idx], bl1 = baseline[idx + 256];
    float g1 = GAMMA_ * (1.f - te);
    float delta = (r + g1 * bl1 - bl) * tm;
    float c = g1 * tm * LAM_;
    Aa = delta + c * Aa;
    Pp = c * Pp;
  }
  A[s * 256 + b] = Aa;
  P[s * 256 + b] = Pp;
}

__global__ void gae_phase3(const float* __restrict__ reward,
                           const float* __restrict__ done,
                           const float* __restrict__ trunc,
                           const float* __restrict__ baseline,
                           const float* __restrict__ A,
                           const float* __restrict__ P,
                           float* __restrict__ adv,
                           float* __restrict__ accum) {
  __shared__ float red[12];
  int s = blockIdx.x, b = threadIdx.x;
  float acc = 0.f;
  #pragma unroll 1
  for (int s2 = 31; s2 > s; --s2)
    acc = A[s2 * 256 + b] + P[s2 * 256 + b] * acc;
  int tend = (s + 1) * 32;
  float vnext = baseline[tend * 256 + b];
  float vs_next = acc + vnext;
  float sa = 0.f, sa2 = 0.f, sv2 = 0.f;
  for (int t = tend - 1; t >= s * 32; --t) {
    int idx = t * 256 + b;
    float r = reward[idx], d = done[idx], tr = trunc[idx];
    float tm = 1.f - tr;
    float te = d * tm;
    float bl = baseline[idx];
    float g1 = GAMMA_ * (1.f - te);
    float delta = (r + g1 * vnext - bl) * tm;
    acc = delta + g1 * tm * LAM_ * acc;
    float at = (r + g1 * vs_next - bl) * tm;
    at = fminf(1e15f, fmaxf(-1e15f, at));
    adv[idx] = at;
    sa += at; sa2 += at * at;
    sv2 += fminf(acc * acc, 1e30f);
    vs_next = acc + bl;
    vnext = bl;
  }
  float v0 = sa, v1 = sa2, v2 = sv2;
  #pragma unroll
  for (int o = 32; o > 0; o >>= 1) {
    v0 += __shfl_down(v0, o, 64);
    v1 += __shfl_down(v1, o, 64);
    v2 += __shfl_down(v2, o, 64);
  }
  int lane = threadIdx.x & 63, w = threadIdx.x >> 6;
  if (lane == 0) { red[w] = v0; red[4 + w] = v1; red[8 + w] = v2; }
  __syncthreads();
  if (threadIdx.x == 0) {
    float s0=0.f, s1=0.f, s2=0.f;
    for (int q = 0; q < 4; ++q) { s0 += red[q]; s1 += red[4+q]; s2 += red[8+q]; }
    atomicAdd(&accum[3], s0);
    atomicAdd(&accum[4], s1);
    atomicAdd(&accum[5], s2);
  }
}

// ---------------- epi2: gp/lp sums + last-block finalize ----------------
__global__ __launch_bounds__(256)
void epi2_kernel(const float* __restrict__ glpA,
                 const float* __restrict__ llpA,
                 const float* __restrict__ blpA,
                 const float* __restrict__ adv,
                 float* __restrict__ accum,
                 float* __restrict__ accumB,
                 float* __restrict__ out) {
  __shared__ float red2[8];
  __shared__ int lastFlag;
  int tid = threadIdx.x;
  long row = (long)blockIdx.x * 256 + tid;

  float glp = glpA[row], llp = llpA[row], blp = blpA[row], av = adv[row];
  float N = (float)ROWS_P;
  float sum = accum[3], sumsq = accum[4];
  float mean = sum / N;
  float var  = fmaxf((sumsq - sum * sum / N) / (N - 1.f), 0.f);
  float inv  = 1.f / (sqrtf(var) + 1e-5f);
  float a_n  = (av - mean) * inv;

  float diff = glp - llp;
  float rho = expf(fminf(glp - blp, 80.f));
  float cl  = fminf(LOG1P2_, fmaxf(LOG0P8_, diff));
  float rc  = expf(fminf(cl + llp - blp, 80.f));
  rc = fminf(1.f + EPSILON_, fmaxf(1.f - EPSILON_, rc));
  float gp = clamp30(fminf(rho * a_n, rc * a_n));

  float rho2 = expf(fminf(llp - blp, 10.f));
  float r2c  = fminf(1.f + EPSILON_, fmaxf(1.f - EPSILON_, rho2));
  float lp = clamp30(fminf(rho2 * a_n, r2c * a_n));

  #pragma unroll
  for (int o = 32; o > 0; o >>= 1) {
    gp += __shfl_down(gp, o, 64);
    lp += __shfl_down(lp, o, 64);
  }
  int lane = tid & 63, w = tid >> 6;
  if (lane == 0) { red2[w] = gp; red2[4 + w] = lp; }
  __syncthreads();
  if (tid == 0) {
    float sg = 0.f, sl = 0.f;
    for (int q = 0; q < 4; ++q) { sg += red2[q]; sl += red2[4 + q]; }
    float* bank = accumB + (blockIdx.x & 31) * 32;
    atomicAdd(&bank[6], sg);
    atomicAdd(&bank[7], sl);
    __threadfence();
    u32 old = atomicAdd((u32*)&accum[24], 1u);
    lastFlag = (old == (u32)(gridDim.x - 1)) ? 1 : 0;
  }
  __syncthreads();
  if (lastFlag) {
    float s0 = 0.f, s1 = 0.f, s2 = 0.f, s6 = 0.f, s7 = 0.f;
    if (tid < 32) {
      float* bank = accumB + tid * 32;
      s0 = atomicAdd(&bank[0], 0.f);   // coherent device-scope reads
      s1 = atomicAdd(&bank[1], 0.f);
      s2 = atomicAdd(&bank[2], 0.f);
      s6 = atomicAdd(&bank[6], 0.f);
      s7 = atomicAdd(&bank[7], 0.f);
    }
    #pragma unroll
    for (int o = 16; o > 0; o >>= 1) {
      s0 += __shfl_down(s0, o, 32);
      s1 += __shfl_down(s1, o, 32);
      s2 += __shfl_down(s2, o, 32);
      s6 += __shfl_down(s6, o, 32);
      s7 += __shfl_down(s7, o, 32);
    }
    if (tid == 0) {
      float kl_learner = s0 / N;
      float kl_guider  = s1 / N;
      float entropy    = s2 / N;
      float v_loss     = 0.25f * accum[5] / N;
      float gp_loss    = -s6 / N;
      float lp_loss    = -s7 / N;
      float learner_loss = kl_learner + lp_loss;      // ALPHA = 1
      float guider_loss  = kl_guider + gp_loss;
      float total = learner_loss + guider_loss + v_loss - 0.01f * entropy;
      out[0] = total;
      out[1] = guider_loss;
      out[2] = learner_loss;
      out[3] = kl_learner;
    }
  }
}

extern "C" void kernel_launch(void* const* d_in, const int* in_sizes, int n_in,
                              void* d_out, int out_size, void* d_ws, size_t ws_size,
                              hipStream_t stream) {
  (void)in_sizes; (void)n_in; (void)out_size; (void)ws_size;
  const float* obs    = (const float*)d_in[0];
  const float* pobs   = (const float*)d_in[1];
  const float* reward = (const float*)d_in[2];
  const float* done   = (const float*)d_in[3];
  const float* trunc  = (const float*)d_in[4];
  const float* logits = (const float*)d_in[5];
  const float* action = (const float*)d_in[6];
  const float* noise  = (const float*)d_in[7];
  const float* pw0 = (const float*)d_in[8];
  const float* pb0 = (const float*)d_in[9];
  const float* pw1 = (const float*)d_in[10];
  const float* pb1 = (const float*)d_in[11];
  const float* pw2 = (const float*)d_in[12];
  const float* pb2 = (const float*)d_in[13];
  const float* vw0 = (const float*)d_in[14];
  const float* vb0 = (const float*)d_in[15];
  const float* vw1 = (const float*)d_in[16];
  const float* vb1 = (const float*)d_in[17];
  const float* vw2 = (const float*)d_in[18];
  const float* vb2 = (const float*)d_in[19];
  const float* rm  = (const float*)d_in[20];
  const float* rv  = (const float*)d_in[21];

  u16*   frag  = (u16*)d_ws;
  float* fbase = (float*)d_ws + FR_TOTAL / 2;
  float* accum   = fbase + WS_ACC;
  float* inv_std = fbase + WS_INV;
  float* adv     = fbase + WS_ADV;
  float* base    = fbase + WS_BASE;
  float* gA      = fbase + WS_GA;
  float* gP      = fbase + WS_GP;
  float* accumB  = fbase + WS_BANK;
  float* glpA    = fbase + WS_GLP;
  float* llpA    = fbase + WS_LLP;
  float* blpA    = fbase + WS_BLP;
  float* out = (float*)d_out;

  convert_kernel<<<672, 256, 0, stream>>>(pw0, pw1, pw2, vw0, vw1, vw2,
                                          rv, inv_std, accum, accumB, frag);

  fused_fwd_kernel<<<12292, 256, 0, stream>>>(
      obs, pobs, rm, inv_std, frag, pb0, pb1, pb2, vb0, vb1, vb2,
      logits, action, noise, base, glpA, llpA, blpA, accumB);

  gae_phase1<<<32, 256, 0, stream>>>(reward, done, trunc, base, gA, gP);
  gae_phase3<<<32, 256, 0, stream>>>(reward, done, trunc, base, gA, gP,
                                     adv, accum);

  epi2_kernel<<<1024, 256, 0, stream>>>(glpA, llpA, blpA, adv,
                                        accum, accumB, out);
}